// Round 11
// baseline (260.070 us; speedup 1.0000x reference)
//
#include <hip/hip_runtime.h>
#include <cstdint>

// CausalSelfAttention fused pipeline, all-bf16 MFMA path.
// R11 = R10 (uniform-work complementary causal pairing, 33 tiles/block) plus:
//  (1) amdgpu_waves_per_eu(4,4): pins the allocator budget at 128 VGPR —
//      R10's allocator squeezed to the 64-reg occupancy step and spilled
//      ~57MB/dispatch of scratch (WRITE 23->74MB) despite launch_bounds(256,4).
//  (2) restored XCD swizzle: R10's decode round-robined the 8 batches sharing
//      a relt panel across 8 XCDs (FETCH 131->311MB). Now same (h,i) -> same
//      bid%8 -> one XCD; per-block relt slice (264KB) is L2-resident.
// ws layout (ushort): Qf[8.39M] Kf[8.39M] Vf[8.39M] XbAO[8.39M] WtQ[786K] WtO[262K] [relt 33.55M]

#define DEVI __device__ __forceinline__

typedef __bf16 bf8 __attribute__((ext_vector_type(8)));
typedef float f4 __attribute__((ext_vector_type(4)));
typedef unsigned short us8 __attribute__((ext_vector_type(8)));
typedef unsigned short us4 __attribute__((ext_vector_type(4)));

typedef const unsigned int __attribute__((address_space(1))) gu32;
typedef unsigned int __attribute__((address_space(3))) lu32;

DEVI unsigned short f2bf(float f) {  // RNE f32->bf16 (no NaN inputs here)
  unsigned u = __builtin_bit_cast(unsigned, f);
  u += 0x7fffu + ((u >> 16) & 1u);
  return (unsigned short)(u >> 16);
}

DEVI void gl_lds16(const void* g, void* l) {
  __builtin_amdgcn_global_load_lds((gu32*)g, (lu32*)l, 16, 0, 0);
}

DEVI bf8 comb(us4 a, us4 b) {
  us8 r;
  r[0]=a[0]; r[1]=a[1]; r[2]=a[2]; r[3]=a[3];
  r[4]=b[0]; r[5]=b[1]; r[6]=b[2]; r[7]=b[3];
  return __builtin_bit_cast(bf8, r);
}

// ---------------- prep: x (f32 [16384][512]) -> bf16, chunk-swizzled ----------------
__global__ __launch_bounds__(256) void k_convert_x(const float* __restrict__ x,
                                                   unsigned short* __restrict__ xb) {
  int c = blockIdx.x * 256 + threadIdx.x;   // 1,048,576 chunks
  int row = c >> 6, cl = c & 63;
  const float* s = x + ((size_t)row << 9) + (cl << 3);
  float4 a = *(const float4*)s;
  float4 b = *(const float4*)(s + 4);
  us8 o;
  o[0]=f2bf(a.x); o[1]=f2bf(a.y); o[2]=f2bf(a.z); o[3]=f2bf(a.w);
  o[4]=f2bf(b.x); o[5]=f2bf(b.y); o[6]=f2bf(b.z); o[7]=f2bf(b.w);
  int p = (cl & ~7) | ((cl & 7) ^ (row & 7));
  *(us8*)(xb + ((size_t)row << 9) + (p << 3)) = o;
}

// ------------- prep: W [512][N] f32 -> Wt [N][512] bf16, chunk-swizzled -------------
__global__ __launch_bounds__(256) void k_transpose_w(const float* __restrict__ W,
                                                     unsigned short* __restrict__ Wt, int N) {
  __shared__ float t[32][33];
  int k0 = blockIdx.x * 32, n0 = blockIdx.y * 32;
  int tx = threadIdx.x & 31, ty = threadIdx.x >> 5;
#pragma unroll
  for (int r = 0; r < 4; ++r)
    t[ty + r * 8][tx] = W[(size_t)(k0 + ty + r * 8) * N + n0 + tx];
  __syncthreads();
#pragma unroll
  for (int r = 0; r < 4; ++r) {
    int n = n0 + ty + r * 8, k = k0 + tx;
    int k2 = (k & ~63) | ((((k >> 3) & 7) ^ (n & 7)) << 3) | (k & 7);
    Wt[((size_t)n << 9) + k2] = f2bf(t[tx][ty + r * 8]);
  }
}

// ---- prep: rel f32 [h][q][k] -> bf16 fragment-ordered table (lower-tri tiles only) ----
__global__ __launch_bounds__(256) void k_relconv(const float* __restrict__ rel,
                                                 unsigned short* __restrict__ relt) {
  int t = blockIdx.x * 256 + threadIdx.x;   // 8.39M threads
  int lane = t & 63, ct = (t >> 6) & 3, kt = (t >> 8) & 31, q16 = (t >> 13) & 127, h = t >> 20;
  if (kt > (q16 >> 2)) return;              // above-diagonal tiles never read
  int row0 = (q16 << 4) + ((lane >> 4) << 2);
  int col = (kt << 6) + (ct << 4) + (lane & 15);
  const float* rp = rel + ((size_t)h << 22) + ((size_t)row0 << 11) + col;
  us4 o;
#pragma unroll
  for (int j = 0; j < 4; ++j) o[j] = f2bf(rp[(size_t)j << 11]);
  size_t idx = ((((((size_t)h << 7) | q16) << 5) | kt) << 2 | ct) << 6 | lane;
  *(us4*)(relt + (idx << 2)) = o;
}

// ---------------- GEMM: C[M][col] = A[M][512] * Bt[col][512]^T + bias ----------------
template <int EPI>
__global__ __launch_bounds__(256, 2)
void k_gemm(const unsigned short* __restrict__ Ag, const unsigned short* __restrict__ Bg,
            const float* __restrict__ bias, float* __restrict__ Of,
            unsigned short* __restrict__ Oq, unsigned short* __restrict__ Ok,
            unsigned short* __restrict__ Ov) {
  __shared__ __align__(16) unsigned short lds[128 * 64 * 2];
  unsigned short* Al = lds;
  unsigned short* Bl = lds + 128 * 64;
  const int tid = threadIdx.x, wv = tid >> 6, lane = tid & 63, g = lane >> 4, cl = lane & 15;
  const int wm = wv >> 1, wn = wv & 1;
  const int row0 = blockIdx.x * 128, col0 = blockIdx.y * 128;
  f4 acc[4][4];
#pragma unroll
  for (int i = 0; i < 4; ++i)
#pragma unroll
    for (int j = 0; j < 4; ++j) acc[i][j] = (f4){0.f, 0.f, 0.f, 0.f};

  for (int kt = 0; kt < 8; ++kt) {
#pragma unroll
    for (int j = 0; j < 4; ++j) {
      int ci = wv * 4 + j;
      int gci = ci * 64 + lane;
      int r = gci >> 3, cc = gci & 7;
      gl_lds16(Ag + ((size_t)(row0 + r) << 9) + kt * 64 + cc * 8, Al + ci * 512);
      gl_lds16(Bg + ((size_t)(col0 + r) << 9) + kt * 64 + cc * 8, Bl + ci * 512);
    }
    __syncthreads();
#pragma unroll
    for (int kk = 0; kk < 2; ++kk) {
      bf8 af[4], bb[4];
#pragma unroll
      for (int mf = 0; mf < 4; ++mf) {
        int r = wm * 64 + mf * 16 + cl;
        int cc = (kk * 4 + g) ^ (r & 7);
        af[mf] = *(const bf8*)(Al + r * 64 + cc * 8);
      }
#pragma unroll
      for (int nf = 0; nf < 4; ++nf) {
        int r = wn * 64 + nf * 16 + cl;
        int cc = (kk * 4 + g) ^ (r & 7);
        bb[nf] = *(const bf8*)(Bl + r * 64 + cc * 8);
      }
#pragma unroll
      for (int mf = 0; mf < 4; ++mf)
#pragma unroll
        for (int nf = 0; nf < 4; ++nf)
          acc[mf][nf] = __builtin_amdgcn_mfma_f32_16x16x32_bf16(af[mf], bb[nf], acc[mf][nf], 0, 0, 0);
    }
    __syncthreads();
  }

  if (EPI == 1) {
#pragma unroll
    for (int nf = 0; nf < 4; ++nf) {
      int col = col0 + wn * 64 + nf * 16 + cl;
      float bv = bias[col];
#pragma unroll
      for (int mf = 0; mf < 4; ++mf) {
#pragma unroll
        for (int j = 0; j < 4; ++j) {
          int row = row0 + wm * 64 + mf * 16 + 4 * g + j;  // C/D: col=lane&15, row=4*(lane>>4)+reg
          Of[((size_t)row << 9) + col] = acc[mf][nf][j] + bv;
        }
      }
    }
  } else {
    const int which = col0 >> 9;   // block-uniform
#pragma unroll
    for (int nf = 0; nf < 4; ++nf) {
      int col = col0 + wn * 64 + nf * 16 + cl;
      float bv = bias[col];
      int d = col & 63, h = (col >> 6) & 7;
#pragma unroll
      for (int mf = 0; mf < 4; ++mf) {
        int row = row0 + wm * 64 + mf * 16 + 4 * g;   // j = 0 row
        int b = row >> 11, s = row & 2047;
        size_t fb = ((size_t)b * 8 + h) * 131072;     // per-(b,h) fragment array
        if (which == 0) {
          // Q frag: [q16][kk][lane][8]; val = Q[s=q16*16+cl][d=kk*32+g*8+j]
#pragma unroll
          for (int j = 0; j < 4; ++j) {
            int ss = s + j;
            size_t off = fb + (size_t)((ss >> 4) * 1024 + (d >> 5) * 512 +
                                       (((d >> 3) & 3) * 16 + (ss & 15)) * 8 + (d & 7));
            Oq[off] = f2bf((acc[mf][nf][j] + bv) * 0.125f);   // fold softmax scale
          }
        } else if (which == 1) {
          // K frag: [kt][kk][ct][lane][8]; val = K[s=kt*64+ct*16+cl][d=kk*32+g*8+j]
#pragma unroll
          for (int j = 0; j < 4; ++j) {
            int ss = s + j;
            size_t off = fb + (size_t)((ss >> 6) * 4096 + (d >> 5) * 2048 + ((ss >> 4) & 3) * 512 +
                                       (((d >> 3) & 3) * 16 + (ss & 15)) * 8 + (d & 7));
            Ok[off] = f2bf(acc[mf][nf][j] + bv);
          }
        } else {
          // V frag: [kt][kk][ct][lane][8]; val = V[s=kt*64+kk*32+g*8+j][d=ct*16+cl]
          us4 o;
#pragma unroll
          for (int j = 0; j < 4; ++j) o[j] = f2bf(acc[mf][nf][j] + bv);
          size_t off = fb + (size_t)((s >> 6) * 4096 + ((s >> 5) & 1) * 2048 + (d >> 4) * 512 +
                                     ((((s >> 3) & 3) * 16) + (d & 15)) * 8 + (s & 7));
          *(us4*)(Ov + off) = o;
        }
      }
    }
  }
}

// ------------------------------- flash attention --------------------------------
// block = (b, h, pair i); wave = early q16A (k 0..i) + late q16B (k 0..31-i).
// Uniform 33 tiles/block. Macros on kernel-local arrays (no pointer escape).

#define ADDRELM(sa, q16X, rX)                                                 \
  do {                                                                        \
    if constexpr (RELT) {                                                     \
      const unsigned short* tb_ =                                             \
          relt + (((((size_t)h << 7) | (q16X)) << 5) | kt_) * 1024;           \
      _Pragma("unroll") for (int ct = 0; ct < 4; ++ct) {                      \
        us4 r_ = *(const us4*)(tb_ + ((ct << 6) | lane) * 4);                 \
        _Pragma("unroll") for (int j = 0; j < 4; ++j)                         \
          sa[ct][j] += __builtin_bit_cast(float, (unsigned)r_[j] << 16);      \
      }                                                                       \
    } else {                                                                  \
      const float* rb_ = relp + ((size_t)((rX) + 4 * g) << 11) + kb_ + cl;    \
      _Pragma("unroll") for (int ct = 0; ct < 4; ++ct)                        \
        _Pragma("unroll") for (int j = 0; j < 4; ++j)                         \
          sa[ct][j] += rb_[((size_t)j << 11) + ct * 16];                      \
    }                                                                         \
  } while (0)

#define MASKM(sa, rX)                                                         \
  do {                                                                        \
    _Pragma("unroll") for (int ct = 0; ct < 4; ++ct) {                        \
      int kcol_ = kb_ + ct * 16 + cl;                                         \
      _Pragma("unroll") for (int j = 0; j < 4; ++j)                           \
        if (kcol_ > (rX) + 4 * g + j) sa[ct][j] = -1e30f;                     \
    }                                                                         \
  } while (0)

// softmax + rescale oa + park P tile in LDS rows [RO, RO+16)
#define SMXM(sa, mr, lr, oa, RO)                                              \
  do {                                                                        \
    float al_[4];                                                             \
    _Pragma("unroll") for (int j = 0; j < 4; ++j) {                           \
      float m0_ = fmaxf(fmaxf(sa[0][j], sa[1][j]), fmaxf(sa[2][j], sa[3][j]));\
      m0_ = fmaxf(m0_, __shfl_xor(m0_, 1, 16));                               \
      m0_ = fmaxf(m0_, __shfl_xor(m0_, 2, 16));                               \
      m0_ = fmaxf(m0_, __shfl_xor(m0_, 4, 16));                               \
      m0_ = fmaxf(m0_, __shfl_xor(m0_, 8, 16));                               \
      float mn_ = fmaxf(mr[j], m0_);                                          \
      al_[j] = __expf(mr[j] - mn_);                                           \
      mr[j] = mn_;                                                            \
    }                                                                         \
    _Pragma("unroll") for (int ct = 0; ct < 4; ++ct)                          \
      _Pragma("unroll") for (int j = 0; j < 4; ++j)                           \
        sa[ct][j] = __expf(sa[ct][j] - mr[j]);                                \
    _Pragma("unroll") for (int j = 0; j < 4; ++j) {                           \
      float rs_ = sa[0][j] + sa[1][j] + sa[2][j] + sa[3][j];                  \
      rs_ += __shfl_xor(rs_, 1, 16);                                          \
      rs_ += __shfl_xor(rs_, 2, 16);                                          \
      rs_ += __shfl_xor(rs_, 4, 16);                                          \
      rs_ += __shfl_xor(rs_, 8, 16);                                          \
      lr[j] = lr[j] * al_[j] + rs_;                                           \
    }                                                                         \
    _Pragma("unroll") for (int ct = 0; ct < 4; ++ct) {                        \
      oa[ct][0] *= al_[0]; oa[ct][1] *= al_[1];                               \
      oa[ct][2] *= al_[2]; oa[ct][3] *= al_[3];                               \
    }                                                                         \
    _Pragma("unroll") for (int ct = 0; ct < 4; ++ct)                          \
      _Pragma("unroll") for (int j = 0; j < 4; ++j)                           \
        pw[((RO) + 4 * g + j) * 68 + ct * 16 + cl] = f2bf(sa[ct][j]);         \
  } while (0)

#define TILEM(KT, AON, ADIAG, BDIAG)                                          \
  do {                                                                        \
    const bool AON_ = (AON), ADIAG_ = (ADIAG), BDIAG_ = (BDIAG);              \
    const int kt_ = (KT), kb_ = kt_ << 6;                                     \
    const unsigned short* Kt_ = Kp + kt_ * 4096;                              \
    const unsigned short* Vt_ = Vp + kt_ * 4096;                              \
    f4 saA[4], saB[4];                                                        \
    _Pragma("unroll") for (int ct = 0; ct < 4; ++ct) {                        \
      saA[ct] = (f4){0.f,0.f,0.f,0.f}; saB[ct] = (f4){0.f,0.f,0.f,0.f};       \
    }                                                                         \
    _Pragma("unroll") for (int kk = 0; kk < 2; ++kk) {                        \
      bf8 kf_[4];                                                             \
      _Pragma("unroll") for (int ct = 0; ct < 4; ++ct)                        \
        kf_[ct] = *(const bf8*)(Kt_ + kk * 2048 + ct * 512 + lane * 8);       \
      if (AON_) {                                                             \
        _Pragma("unroll") for (int ct = 0; ct < 4; ++ct)                      \
          saA[ct] = __builtin_amdgcn_mfma_f32_16x16x32_bf16(qfA[kk], kf_[ct], \
                                                            saA[ct], 0, 0, 0);\
      }                                                                       \
      _Pragma("unroll") for (int ct = 0; ct < 4; ++ct)                        \
        saB[ct] = __builtin_amdgcn_mfma_f32_16x16x32_bf16(qfB[kk], kf_[ct],   \
                                                          saB[ct], 0, 0, 0);  \
    }                                                                         \
    if (AON_) ADDRELM(saA, q16A, rA);                                         \
    ADDRELM(saB, q16B, rB);                                                   \
    if (ADIAG_) MASKM(saA, rA);                                               \
    if (BDIAG_) MASKM(saB, rB);                                               \
    if (AON_) SMXM(saA, mA, lA, oaA, 0);                                      \
    SMXM(saB, mB, lB, oaB, 16);                                               \
    _Pragma("unroll") for (int kk = 0; kk < 2; ++kk) {                        \
      bf8 vf_[4];                                                             \
      _Pragma("unroll") for (int ct = 0; ct < 4; ++ct)                        \
        vf_[ct] = *(const bf8*)(Vt_ + kk * 2048 + ct * 512 + lane * 8);       \
      if (AON_) {                                                             \
        us4 p0_ = *(const us4*)(pw + cl * 68 + kk * 32 + g * 8);              \
        us4 p1_ = *(const us4*)(pw + cl * 68 + kk * 32 + g * 8 + 4);          \
        bf8 pf_ = comb(p0_, p1_);                                             \
        _Pragma("unroll") for (int ct = 0; ct < 4; ++ct)                      \
          oaA[ct] = __builtin_amdgcn_mfma_f32_16x16x32_bf16(pf_, vf_[ct],     \
                                                            oaA[ct], 0, 0, 0);\
      }                                                                       \
      {                                                                       \
        us4 p0_ = *(const us4*)(pw + (16 + cl) * 68 + kk * 32 + g * 8);       \
        us4 p1_ = *(const us4*)(pw + (16 + cl) * 68 + kk * 32 + g * 8 + 4);   \
        bf8 pf_ = comb(p0_, p1_);                                             \
        _Pragma("unroll") for (int ct = 0; ct < 4; ++ct)                      \
          oaB[ct] = __builtin_amdgcn_mfma_f32_16x16x32_bf16(pf_, vf_[ct],     \
                                                            oaB[ct], 0, 0, 0);\
      }                                                                       \
    }                                                                         \
  } while (0)

template <bool RELT>
__global__ __launch_bounds__(256) __attribute__((amdgpu_waves_per_eu(4, 4)))
void k_attn(const unsigned short* __restrict__ Qf, const unsigned short* __restrict__ Kf,
            const unsigned short* __restrict__ Vf, const float* __restrict__ rel,
            const unsigned short* __restrict__ relt, unsigned short* __restrict__ AO) {
  __shared__ __align__(16) unsigned short Pl[4][32 * 68];
  const int tid = threadIdx.x, wv = tid >> 6, lane = tid & 63, g = lane >> 4, cl = lane & 15;
  // XCD swizzle: bid = glo + 8*b + 64*chi; c = chi*8+glo -> (h,i). The 8 batches
  // sharing relt panel (h,i) have equal bid%8 -> same XCD L2.
  int bid = blockIdx.x;                        // 1024 uniform blocks
  int glo = bid & 7, b = (bid >> 3) & 7, chi = bid >> 6;
  int c = chi * 8 + glo;                       // 0..127
  int h = c >> 4, i = c & 15;                  // pair index i = 0..15
  const int iA = i, kBt = 31 - i;
  const int q16A = 4 * i + wv, q16B = 4 * (31 - i) + wv;
  const int rA = q16A << 4, rB = q16B << 4;
  size_t fb = (((size_t)b << 3) + h) * 131072;
  const unsigned short* Qp = Qf + fb;
  const unsigned short* Kp = Kf + fb;
  const unsigned short* Vp = Vf + fb;
  const float* relp = rel + ((size_t)h << 22);

  bf8 qfA[2], qfB[2];
#pragma unroll
  for (int kk = 0; kk < 2; ++kk) {
    qfA[kk] = *(const bf8*)(Qp + q16A * 1024 + kk * 512 + lane * 8);
    qfB[kk] = *(const bf8*)(Qp + q16B * 1024 + kk * 512 + lane * 8);
  }

  f4 oaA[4], oaB[4];
  float mA[4], lA[4], mB[4], lB[4];
#pragma unroll
  for (int j = 0; j < 4; ++j) { mA[j] = -1e30f; lA[j] = 0.f; mB[j] = -1e30f; lB[j] = 0.f; }
#pragma unroll
  for (int ct = 0; ct < 4; ++ct) { oaA[ct] = (f4){0.f,0.f,0.f,0.f}; oaB[ct] = (f4){0.f,0.f,0.f,0.f}; }

  unsigned short* pw = Pl[wv];

  for (int kt = 0; kt < iA; ++kt) TILEM(kt, true, false, false);   // shared prefix
  TILEM(iA, true, true, false);                                    // A diagonal
  for (int kt = iA + 1; kt < kBt; ++kt) TILEM(kt, false, false, false);  // B interior
  TILEM(kBt, false, false, true);                                  // B diagonal

  // epilogue: O /= l, write bf16 [b][s][h*64+d] chunk-swizzled for out-GEMM staging
#pragma unroll
  for (int j = 0; j < 4; ++j) {
    float invA = 1.0f / lA[j], invB = 1.0f / lB[j];
    int sA_ = rA + 4 * g + j, sB_ = rB + 4 * g + j;   // sA_&7 == sB_&7
#pragma unroll
    for (int ct = 0; ct < 4; ++ct) {
      int d = ct * 16 + cl;
      int d2 = (d & 7) | (((d >> 3) ^ (sA_ & 7)) << 3);
      AO[(((size_t)b << 11) + sA_) * 512 + h * 64 + d2] = f2bf(oaA[ct][j] * invA);
      AO[(((size_t)b << 11) + sB_) * 512 + h * 64 + d2] = f2bf(oaB[ct][j] * invB);
    }
  }
}

// ------------------------------------ launch ------------------------------------
extern "C" void kernel_launch(void* const* d_in, const int* in_sizes, int n_in,
                              void* d_out, int out_size, void* d_ws, size_t ws_size,
                              hipStream_t stream) {
  const float* x    = (const float*)d_in[0];
  const float* Wqkv = (const float*)d_in[1];
  const float* bqkv = (const float*)d_in[2];
  const float* Wout = (const float*)d_in[3];
  const float* bout = (const float*)d_in[4];
  const float* rel  = (const float*)d_in[5];
  float* out = (float*)d_out;

  unsigned short* Qw  = (unsigned short*)d_ws;
  unsigned short* Kw  = Qw  + 8388608;
  unsigned short* Vw  = Kw  + 8388608;
  unsigned short* XA  = Vw  + 8388608;    // Xb (pre-attn) then AO (post-attn)
  unsigned short* WtQ = XA  + 8388608;
  unsigned short* WtO = WtQ + 786432;
  unsigned short* relt= WtO + 262144;
  const bool useT = ws_size >= (34603008ULL + 33554432ULL) * 2ULL;  // base + rel table

  k_convert_x<<<dim3(4096), dim3(256), 0, stream>>>(x, XA);
  k_transpose_w<<<dim3(16, 48), dim3(256), 0, stream>>>(Wqkv, WtQ, 1536);
  k_transpose_w<<<dim3(16, 16), dim3(256), 0, stream>>>(Wout, WtO, 512);
  if (useT) k_relconv<<<dim3(32768), dim3(256), 0, stream>>>(rel, relt);
  k_gemm<0><<<dim3(128, 12), dim3(256), 0, stream>>>(XA, WtQ, bqkv, nullptr, Qw, Kw, Vw);
  if (useT) k_attn<true ><<<dim3(1024), dim3(256), 0, stream>>>(Qw, Kw, Vw, rel, relt, XA);
  else      k_attn<false><<<dim3(1024), dim3(256), 0, stream>>>(Qw, Kw, Vw, rel, relt, XA);
  k_gemm<1><<<dim3(128, 4), dim3(256), 0, stream>>>(XA, WtO, bout, out, nullptr, nullptr, nullptr);
}

// Round 12
// 216.381 us; speedup vs baseline: 1.2019x; 1.2019x over previous
//
#include <hip/hip_runtime.h>
#include <cstdint>

// CausalSelfAttention fused pipeline, all-bf16 MFMA path.
// R12: SEQUENTIAL two-pass attention blocks. R10/R11's paired A/B pipelines
// held 2x wave state; the allocator insisted on the 64-VGPR tier and spilled
// ~53MB/dispatch (+53MB readback = ~1/3 of FETCH). Now block (b,h,i) runs
// slab A (q16 4i+wv, k 0..i) to completion, THEN slab B (4(31-i)+wv, k 0..31-i):
// one pipeline live at a time (~85 regs, the R9 spill-free shape), still 33
// uniform tiles/block, occupancy stays ~40%. K/V prefix re-read is L2-hot.
// ws layout (ushort): Qf[8.39M] Kf[8.39M] Vf[8.39M] XbAO[8.39M] WtQ[786K] WtO[262K] [relt 33.55M]

#define DEVI __device__ __forceinline__

typedef __bf16 bf8 __attribute__((ext_vector_type(8)));
typedef float f4 __attribute__((ext_vector_type(4)));
typedef unsigned short us8 __attribute__((ext_vector_type(8)));
typedef unsigned short us4 __attribute__((ext_vector_type(4)));

typedef const unsigned int __attribute__((address_space(1))) gu32;
typedef unsigned int __attribute__((address_space(3))) lu32;

DEVI unsigned short f2bf(float f) {  // RNE f32->bf16 (no NaN inputs here)
  unsigned u = __builtin_bit_cast(unsigned, f);
  u += 0x7fffu + ((u >> 16) & 1u);
  return (unsigned short)(u >> 16);
}

DEVI void gl_lds16(const void* g, void* l) {
  __builtin_amdgcn_global_load_lds((gu32*)g, (lu32*)l, 16, 0, 0);
}

DEVI bf8 comb(us4 a, us4 b) {
  us8 r;
  r[0]=a[0]; r[1]=a[1]; r[2]=a[2]; r[3]=a[3];
  r[4]=b[0]; r[5]=b[1]; r[6]=b[2]; r[7]=b[3];
  return __builtin_bit_cast(bf8, r);
}

// ---------------- prep: x (f32 [16384][512]) -> bf16, chunk-swizzled ----------------
__global__ __launch_bounds__(256) void k_convert_x(const float* __restrict__ x,
                                                   unsigned short* __restrict__ xb) {
  int c = blockIdx.x * 256 + threadIdx.x;   // 1,048,576 chunks
  int row = c >> 6, cl = c & 63;
  const float* s = x + ((size_t)row << 9) + (cl << 3);
  float4 a = *(const float4*)s;
  float4 b = *(const float4*)(s + 4);
  us8 o;
  o[0]=f2bf(a.x); o[1]=f2bf(a.y); o[2]=f2bf(a.z); o[3]=f2bf(a.w);
  o[4]=f2bf(b.x); o[5]=f2bf(b.y); o[6]=f2bf(b.z); o[7]=f2bf(b.w);
  int p = (cl & ~7) | ((cl & 7) ^ (row & 7));
  *(us8*)(xb + ((size_t)row << 9) + (p << 3)) = o;
}

// ------------- prep: W [512][N] f32 -> Wt [N][512] bf16, chunk-swizzled -------------
__global__ __launch_bounds__(256) void k_transpose_w(const float* __restrict__ W,
                                                     unsigned short* __restrict__ Wt, int N) {
  __shared__ float t[32][33];
  int k0 = blockIdx.x * 32, n0 = blockIdx.y * 32;
  int tx = threadIdx.x & 31, ty = threadIdx.x >> 5;
#pragma unroll
  for (int r = 0; r < 4; ++r)
    t[ty + r * 8][tx] = W[(size_t)(k0 + ty + r * 8) * N + n0 + tx];
  __syncthreads();
#pragma unroll
  for (int r = 0; r < 4; ++r) {
    int n = n0 + ty + r * 8, k = k0 + tx;
    int k2 = (k & ~63) | ((((k >> 3) & 7) ^ (n & 7)) << 3) | (k & 7);
    Wt[((size_t)n << 9) + k2] = f2bf(t[tx][ty + r * 8]);
  }
}

// ---- prep: rel f32 [h][q][k] -> bf16 fragment-ordered table (lower-tri tiles only) ----
__global__ __launch_bounds__(256) void k_relconv(const float* __restrict__ rel,
                                                 unsigned short* __restrict__ relt) {
  int t = blockIdx.x * 256 + threadIdx.x;   // 8.39M threads
  int lane = t & 63, ct = (t >> 6) & 3, kt = (t >> 8) & 31, q16 = (t >> 13) & 127, h = t >> 20;
  if (kt > (q16 >> 2)) return;              // above-diagonal tiles never read
  int row0 = (q16 << 4) + ((lane >> 4) << 2);
  int col = (kt << 6) + (ct << 4) + (lane & 15);
  const float* rp = rel + ((size_t)h << 22) + ((size_t)row0 << 11) + col;
  us4 o;
#pragma unroll
  for (int j = 0; j < 4; ++j) o[j] = f2bf(rp[(size_t)j << 11]);
  size_t idx = ((((((size_t)h << 7) | q16) << 5) | kt) << 2 | ct) << 6 | lane;
  *(us4*)(relt + (idx << 2)) = o;
}

// ---------------- GEMM: C[M][col] = A[M][512] * Bt[col][512]^T + bias ----------------
template <int EPI>
__global__ __launch_bounds__(256, 2)
void k_gemm(const unsigned short* __restrict__ Ag, const unsigned short* __restrict__ Bg,
            const float* __restrict__ bias, float* __restrict__ Of,
            unsigned short* __restrict__ Oq, unsigned short* __restrict__ Ok,
            unsigned short* __restrict__ Ov) {
  __shared__ __align__(16) unsigned short lds[128 * 64 * 2];
  unsigned short* Al = lds;
  unsigned short* Bl = lds + 128 * 64;
  const int tid = threadIdx.x, wv = tid >> 6, lane = tid & 63, g = lane >> 4, cl = lane & 15;
  const int wm = wv >> 1, wn = wv & 1;
  const int row0 = blockIdx.x * 128, col0 = blockIdx.y * 128;
  f4 acc[4][4];
#pragma unroll
  for (int i = 0; i < 4; ++i)
#pragma unroll
    for (int j = 0; j < 4; ++j) acc[i][j] = (f4){0.f, 0.f, 0.f, 0.f};

  for (int kt = 0; kt < 8; ++kt) {
#pragma unroll
    for (int j = 0; j < 4; ++j) {
      int ci = wv * 4 + j;
      int gci = ci * 64 + lane;
      int r = gci >> 3, cc = gci & 7;
      gl_lds16(Ag + ((size_t)(row0 + r) << 9) + kt * 64 + cc * 8, Al + ci * 512);
      gl_lds16(Bg + ((size_t)(col0 + r) << 9) + kt * 64 + cc * 8, Bl + ci * 512);
    }
    __syncthreads();
#pragma unroll
    for (int kk = 0; kk < 2; ++kk) {
      bf8 af[4], bb[4];
#pragma unroll
      for (int mf = 0; mf < 4; ++mf) {
        int r = wm * 64 + mf * 16 + cl;
        int cc = (kk * 4 + g) ^ (r & 7);
        af[mf] = *(const bf8*)(Al + r * 64 + cc * 8);
      }
#pragma unroll
      for (int nf = 0; nf < 4; ++nf) {
        int r = wn * 64 + nf * 16 + cl;
        int cc = (kk * 4 + g) ^ (r & 7);
        bb[nf] = *(const bf8*)(Bl + r * 64 + cc * 8);
      }
#pragma unroll
      for (int mf = 0; mf < 4; ++mf)
#pragma unroll
        for (int nf = 0; nf < 4; ++nf)
          acc[mf][nf] = __builtin_amdgcn_mfma_f32_16x16x32_bf16(af[mf], bb[nf], acc[mf][nf], 0, 0, 0);
    }
    __syncthreads();
  }

  if (EPI == 1) {
#pragma unroll
    for (int nf = 0; nf < 4; ++nf) {
      int col = col0 + wn * 64 + nf * 16 + cl;
      float bv = bias[col];
#pragma unroll
      for (int mf = 0; mf < 4; ++mf) {
#pragma unroll
        for (int j = 0; j < 4; ++j) {
          int row = row0 + wm * 64 + mf * 16 + 4 * g + j;  // C/D: col=lane&15, row=4*(lane>>4)+reg
          Of[((size_t)row << 9) + col] = acc[mf][nf][j] + bv;
        }
      }
    }
  } else {
    const int which = col0 >> 9;   // block-uniform
#pragma unroll
    for (int nf = 0; nf < 4; ++nf) {
      int col = col0 + wn * 64 + nf * 16 + cl;
      float bv = bias[col];
      int d = col & 63, h = (col >> 6) & 7;
#pragma unroll
      for (int mf = 0; mf < 4; ++mf) {
        int row = row0 + wm * 64 + mf * 16 + 4 * g;   // j = 0 row
        int b = row >> 11, s = row & 2047;
        size_t fb = ((size_t)b * 8 + h) * 131072;     // per-(b,h) fragment array
        if (which == 0) {
          // Q frag: [q16][kk][lane][8]; val = Q[s=q16*16+cl][d=kk*32+g*8+j]
#pragma unroll
          for (int j = 0; j < 4; ++j) {
            int ss = s + j;
            size_t off = fb + (size_t)((ss >> 4) * 1024 + (d >> 5) * 512 +
                                       (((d >> 3) & 3) * 16 + (ss & 15)) * 8 + (d & 7));
            Oq[off] = f2bf((acc[mf][nf][j] + bv) * 0.125f);   // fold softmax scale
          }
        } else if (which == 1) {
          // K frag: [kt][kk][ct][lane][8]; val = K[s=kt*64+ct*16+cl][d=kk*32+g*8+j]
#pragma unroll
          for (int j = 0; j < 4; ++j) {
            int ss = s + j;
            size_t off = fb + (size_t)((ss >> 6) * 4096 + (d >> 5) * 2048 + ((ss >> 4) & 3) * 512 +
                                       (((d >> 3) & 3) * 16 + (ss & 15)) * 8 + (d & 7));
            Ok[off] = f2bf(acc[mf][nf][j] + bv);
          }
        } else {
          // V frag: [kt][kk][ct][lane][8]; val = V[s=kt*64+kk*32+g*8+j][d=ct*16+cl]
          us4 o;
#pragma unroll
          for (int j = 0; j < 4; ++j) o[j] = f2bf(acc[mf][nf][j] + bv);
          size_t off = fb + (size_t)((s >> 6) * 4096 + ((s >> 5) & 1) * 2048 + (d >> 4) * 512 +
                                     ((((s >> 3) & 3) * 16) + (d & 15)) * 8 + (s & 7));
          *(us4*)(Ov + off) = o;
        }
      }
    }
  }
}

// ------------------------------- flash attention --------------------------------
// block = (b, h, pair i); TWO SEQUENTIAL passes: slab A (q16=4i+wv, k 0..i) then
// slab B (q16=4(31-i)+wv, k 0..31-i). 33 uniform tiles/block; one pipeline live.
template <bool RELT>
__global__ __launch_bounds__(256, 4)
void k_attn(const unsigned short* __restrict__ Qf, const unsigned short* __restrict__ Kf,
            const unsigned short* __restrict__ Vf, const float* __restrict__ rel,
            const unsigned short* __restrict__ relt, unsigned short* __restrict__ AO) {
  __shared__ __align__(16) unsigned short Pl[4][16 * 68];
  const int tid = threadIdx.x, wv = tid >> 6, lane = tid & 63, g = lane >> 4, cl = lane & 15;
  // XCD swizzle: the 8 batches sharing relt panel (h,i) have equal bid%8 -> same XCD L2.
  int bid = blockIdx.x;                        // 1024 uniform blocks
  int glo = bid & 7, b = (bid >> 3) & 7, chi = bid >> 6;
  int c = chi * 8 + glo;                       // 0..127
  int h = c >> 4, i = c & 15;                  // pair index i = 0..15
  size_t fb = (((size_t)b << 3) + h) * 131072;
  const unsigned short* Qp = Qf + fb;
  const unsigned short* Kp = Kf + fb;
  const unsigned short* Vp = Vf + fb;
  const float* relp = rel + ((size_t)h << 22);
  unsigned short* pw = Pl[wv];

  for (int pass = 0; pass < 2; ++pass) {
    const int slab = pass ? (31 - i) : i;      // 0..31
    const int q16 = 4 * slab + wv;
    const int rX = q16 << 4;
    const int ktop = slab;                     // diagonal k-tile index

    bf8 qf[2];
#pragma unroll
    for (int kk = 0; kk < 2; ++kk)
      qf[kk] = *(const bf8*)(Qp + q16 * 1024 + kk * 512 + lane * 8);

    f4 oa[4];
    float mr[4], lr[4];
#pragma unroll
    for (int j = 0; j < 4; ++j) { mr[j] = -1e30f; lr[j] = 0.f; }
#pragma unroll
    for (int ct = 0; ct < 4; ++ct) oa[ct] = (f4){0.f, 0.f, 0.f, 0.f};

    for (int kt = 0; kt <= ktop; ++kt) {
      const int kb = kt << 6;
      const unsigned short* Kt = Kp + kt * 4096;
      const unsigned short* Vt = Vp + kt * 4096;
      // ---- K fragments (coalesced, 1KB/instr) ----
      bf8 kf[2][4];
#pragma unroll
      for (int kk = 0; kk < 2; ++kk)
#pragma unroll
        for (int ct = 0; ct < 4; ++ct)
          kf[kk][ct] = *(const bf8*)(Kt + kk * 2048 + ct * 512 + lane * 8);
      // ---- QK^T ----
      f4 sa[4];
#pragma unroll
      for (int ct = 0; ct < 4; ++ct) sa[ct] = (f4){0.f, 0.f, 0.f, 0.f};
#pragma unroll
      for (int kk = 0; kk < 2; ++kk)
#pragma unroll
        for (int ct = 0; ct < 4; ++ct)
          sa[ct] = __builtin_amdgcn_mfma_f32_16x16x32_bf16(qf[kk], kf[kk][ct], sa[ct], 0, 0, 0);
      // ---- rel_pos ----
      if constexpr (RELT) {
        const unsigned short* tb = relt + (((((size_t)h << 7) | q16) << 5) | kt) * 1024;
#pragma unroll
        for (int ct = 0; ct < 4; ++ct) {
          us4 r = *(const us4*)(tb + ((ct << 6) | lane) * 4);
#pragma unroll
          for (int j = 0; j < 4; ++j)
            sa[ct][j] += __builtin_bit_cast(float, (unsigned)r[j] << 16);
        }
      } else {
        const float* rb = relp + ((size_t)(rX + 4 * g) << 11) + kb + cl;
#pragma unroll
        for (int ct = 0; ct < 4; ++ct)
#pragma unroll
          for (int j = 0; j < 4; ++j) sa[ct][j] += rb[((size_t)j << 11) + ct * 16];
      }
      // ---- causal mask (diagonal tile only) ----
      if (kt == ktop) {
#pragma unroll
        for (int ct = 0; ct < 4; ++ct) {
          int kcol = kb + ct * 16 + cl;
#pragma unroll
          for (int j = 0; j < 4; ++j)
            if (kcol > rX + 4 * g + j) sa[ct][j] = -1e30f;
        }
      }
      // ---- online softmax (rows in 16-lane groups) ----
      float al[4];
#pragma unroll
      for (int j = 0; j < 4; ++j) {
        float m0 = fmaxf(fmaxf(sa[0][j], sa[1][j]), fmaxf(sa[2][j], sa[3][j]));
        m0 = fmaxf(m0, __shfl_xor(m0, 1, 16));
        m0 = fmaxf(m0, __shfl_xor(m0, 2, 16));
        m0 = fmaxf(m0, __shfl_xor(m0, 4, 16));
        m0 = fmaxf(m0, __shfl_xor(m0, 8, 16));
        float mn = fmaxf(mr[j], m0);
        al[j] = __expf(mr[j] - mn);
        mr[j] = mn;
      }
#pragma unroll
      for (int ct = 0; ct < 4; ++ct)
#pragma unroll
        for (int j = 0; j < 4; ++j) sa[ct][j] = __expf(sa[ct][j] - mr[j]);
#pragma unroll
      for (int j = 0; j < 4; ++j) {
        float rs = sa[0][j] + sa[1][j] + sa[2][j] + sa[3][j];
        rs += __shfl_xor(rs, 1, 16);
        rs += __shfl_xor(rs, 2, 16);
        rs += __shfl_xor(rs, 4, 16);
        rs += __shfl_xor(rs, 8, 16);
        lr[j] = lr[j] * al[j] + rs;
      }
#pragma unroll
      for (int ct = 0; ct < 4; ++ct) {
        oa[ct][0] *= al[0]; oa[ct][1] *= al[1]; oa[ct][2] *= al[2]; oa[ct][3] *= al[3];
      }
      // ---- P -> LDS transpose (wave-private; same-wave DS ordering) ----
#pragma unroll
      for (int ct = 0; ct < 4; ++ct)
#pragma unroll
        for (int j = 0; j < 4; ++j)
          pw[(4 * g + j) * 68 + ct * 16 + cl] = f2bf(sa[ct][j]);
      // ---- PV ----
#pragma unroll
      for (int kk = 0; kk < 2; ++kk) {
        bf8 vf[4];
#pragma unroll
        for (int ct = 0; ct < 4; ++ct)
          vf[ct] = *(const bf8*)(Vt + kk * 2048 + ct * 512 + lane * 8);
        us4 p0 = *(const us4*)(pw + cl * 68 + kk * 32 + g * 8);
        us4 p1 = *(const us4*)(pw + cl * 68 + kk * 32 + g * 8 + 4);
        bf8 pf = comb(p0, p1);
#pragma unroll
        for (int ct = 0; ct < 4; ++ct)
          oa[ct] = __builtin_amdgcn_mfma_f32_16x16x32_bf16(pf, vf[ct], oa[ct], 0, 0, 0);
      }
    }
    // ---- epilogue for this slab: O /= l, chunk-swizzled bf16 write ----
#pragma unroll
    for (int j = 0; j < 4; ++j) {
      float inv = 1.0f / lr[j];
      int s = rX + 4 * g + j;
#pragma unroll
      for (int ct = 0; ct < 4; ++ct) {
        int d = ct * 16 + cl;
        int d2 = (d & 7) | (((d >> 3) ^ (s & 7)) << 3);
        AO[(((size_t)b << 11) + s) * 512 + h * 64 + d2] = f2bf(oa[ct][j] * inv);
      }
    }
  }
}

// ------------------------------------ launch ------------------------------------
extern "C" void kernel_launch(void* const* d_in, const int* in_sizes, int n_in,
                              void* d_out, int out_size, void* d_ws, size_t ws_size,
                              hipStream_t stream) {
  const float* x    = (const float*)d_in[0];
  const float* Wqkv = (const float*)d_in[1];
  const float* bqkv = (const float*)d_in[2];
  const float* Wout = (const float*)d_in[3];
  const float* bout = (const float*)d_in[4];
  const float* rel  = (const float*)d_in[5];
  float* out = (float*)d_out;

  unsigned short* Qw  = (unsigned short*)d_ws;
  unsigned short* Kw  = Qw  + 8388608;
  unsigned short* Vw  = Kw  + 8388608;
  unsigned short* XA  = Vw  + 8388608;    // Xb (pre-attn) then AO (post-attn)
  unsigned short* WtQ = XA  + 8388608;
  unsigned short* WtO = WtQ + 786432;
  unsigned short* relt= WtO + 262144;
  const bool useT = ws_size >= (34603008ULL + 33554432ULL) * 2ULL;  // base + rel table

  k_convert_x<<<dim3(4096), dim3(256), 0, stream>>>(x, XA);
  k_transpose_w<<<dim3(16, 48), dim3(256), 0, stream>>>(Wqkv, WtQ, 1536);
  k_transpose_w<<<dim3(16, 16), dim3(256), 0, stream>>>(Wout, WtO, 512);
  if (useT) k_relconv<<<dim3(32768), dim3(256), 0, stream>>>(rel, relt);
  k_gemm<0><<<dim3(128, 12), dim3(256), 0, stream>>>(XA, WtQ, bqkv, nullptr, Qw, Kw, Vw);
  if (useT) k_attn<true ><<<dim3(1024), dim3(256), 0, stream>>>(Qw, Kw, Vw, rel, relt, XA);
  else      k_attn<false><<<dim3(1024), dim3(256), 0, stream>>>(Qw, Kw, Vw, rel, relt, XA);
  k_gemm<1><<<dim3(128, 4), dim3(256), 0, stream>>>(XA, WtO, bout, out, nullptr, nullptr, nullptr);
}

// Round 13
// 210.887 us; speedup vs baseline: 1.2332x; 1.0261x over previous
//
#include <hip/hip_runtime.h>
#include <cstdint>

// CausalSelfAttention fused pipeline, all-bf16 MFMA path.
// R13 = R12 (sequential two-pass, uniform 33 tiles/block, spill-free) plus:
//  (1) V-fragment + rel loads issued at TILE TOP (R12 loaded V after softmax —
//      exposed ~500cy in every tile tail; FIFO vmcnt lets QK^T wait only on K).
//  (2) P/AO bf16 via compiler (__bf16) casts -> paired v_cvt_pk_bf16_f32
//      (hand-rolled RNE f2bf was 3 VALU ops/value).
//  (3) launch_bounds(256,4): occupancy is grid-limited at 4 waves/SIMD, so a
//      128-VGPR budget is free — room for the now-longer live ranges.
// ws layout (ushort): Qf[8.39M] Kf[8.39M] Vf[8.39M] XbAO[8.39M] WtQ[786K] WtO[262K] [relt 33.55M]

#define DEVI __device__ __forceinline__

typedef __bf16 bf8 __attribute__((ext_vector_type(8)));
typedef float f4 __attribute__((ext_vector_type(4)));
typedef unsigned short us8 __attribute__((ext_vector_type(8)));
typedef unsigned short us4 __attribute__((ext_vector_type(4)));

typedef const unsigned int __attribute__((address_space(1))) gu32;
typedef unsigned int __attribute__((address_space(3))) lu32;

DEVI unsigned short f2bf(float f) {  // RNE f32->bf16 (prep/GEMM epilogues)
  unsigned u = __builtin_bit_cast(unsigned, f);
  u += 0x7fffu + ((u >> 16) & 1u);
  return (unsigned short)(u >> 16);
}

DEVI unsigned short cbf(float f) {   // compiler-lowered cast (v_cvt_pk_bf16_f32 pairs)
  return __builtin_bit_cast(unsigned short, (__bf16)f);
}

DEVI void gl_lds16(const void* g, void* l) {
  __builtin_amdgcn_global_load_lds((gu32*)g, (lu32*)l, 16, 0, 0);
}

DEVI bf8 comb(us4 a, us4 b) {
  us8 r;
  r[0]=a[0]; r[1]=a[1]; r[2]=a[2]; r[3]=a[3];
  r[4]=b[0]; r[5]=b[1]; r[6]=b[2]; r[7]=b[3];
  return __builtin_bit_cast(bf8, r);
}

// ---------------- prep: x (f32 [16384][512]) -> bf16, chunk-swizzled ----------------
__global__ __launch_bounds__(256) void k_convert_x(const float* __restrict__ x,
                                                   unsigned short* __restrict__ xb) {
  int c = blockIdx.x * 256 + threadIdx.x;   // 1,048,576 chunks
  int row = c >> 6, cl = c & 63;
  const float* s = x + ((size_t)row << 9) + (cl << 3);
  float4 a = *(const float4*)s;
  float4 b = *(const float4*)(s + 4);
  us8 o;
  o[0]=f2bf(a.x); o[1]=f2bf(a.y); o[2]=f2bf(a.z); o[3]=f2bf(a.w);
  o[4]=f2bf(b.x); o[5]=f2bf(b.y); o[6]=f2bf(b.z); o[7]=f2bf(b.w);
  int p = (cl & ~7) | ((cl & 7) ^ (row & 7));
  *(us8*)(xb + ((size_t)row << 9) + (p << 3)) = o;
}

// ------------- prep: W [512][N] f32 -> Wt [N][512] bf16, chunk-swizzled -------------
__global__ __launch_bounds__(256) void k_transpose_w(const float* __restrict__ W,
                                                     unsigned short* __restrict__ Wt, int N) {
  __shared__ float t[32][33];
  int k0 = blockIdx.x * 32, n0 = blockIdx.y * 32;
  int tx = threadIdx.x & 31, ty = threadIdx.x >> 5;
#pragma unroll
  for (int r = 0; r < 4; ++r)
    t[ty + r * 8][tx] = W[(size_t)(k0 + ty + r * 8) * N + n0 + tx];
  __syncthreads();
#pragma unroll
  for (int r = 0; r < 4; ++r) {
    int n = n0 + ty + r * 8, k = k0 + tx;
    int k2 = (k & ~63) | ((((k >> 3) & 7) ^ (n & 7)) << 3) | (k & 7);
    Wt[((size_t)n << 9) + k2] = f2bf(t[tx][ty + r * 8]);
  }
}

// ---- prep: rel f32 [h][q][k] -> bf16 fragment-ordered table (lower-tri tiles only) ----
__global__ __launch_bounds__(256) void k_relconv(const float* __restrict__ rel,
                                                 unsigned short* __restrict__ relt) {
  int t = blockIdx.x * 256 + threadIdx.x;   // 8.39M threads
  int lane = t & 63, ct = (t >> 6) & 3, kt = (t >> 8) & 31, q16 = (t >> 13) & 127, h = t >> 20;
  if (kt > (q16 >> 2)) return;              // above-diagonal tiles never read
  int row0 = (q16 << 4) + ((lane >> 4) << 2);
  int col = (kt << 6) + (ct << 4) + (lane & 15);
  const float* rp = rel + ((size_t)h << 22) + ((size_t)row0 << 11) + col;
  us4 o;
#pragma unroll
  for (int j = 0; j < 4; ++j) o[j] = f2bf(rp[(size_t)j << 11]);
  size_t idx = ((((((size_t)h << 7) | q16) << 5) | kt) << 2 | ct) << 6 | lane;
  *(us4*)(relt + (idx << 2)) = o;
}

// ---------------- GEMM: C[M][col] = A[M][512] * Bt[col][512]^T + bias ----------------
template <int EPI>
__global__ __launch_bounds__(256, 2)
void k_gemm(const unsigned short* __restrict__ Ag, const unsigned short* __restrict__ Bg,
            const float* __restrict__ bias, float* __restrict__ Of,
            unsigned short* __restrict__ Oq, unsigned short* __restrict__ Ok,
            unsigned short* __restrict__ Ov) {
  __shared__ __align__(16) unsigned short lds[128 * 64 * 2];
  unsigned short* Al = lds;
  unsigned short* Bl = lds + 128 * 64;
  const int tid = threadIdx.x, wv = tid >> 6, lane = tid & 63, g = lane >> 4, cl = lane & 15;
  const int wm = wv >> 1, wn = wv & 1;
  const int row0 = blockIdx.x * 128, col0 = blockIdx.y * 128;
  f4 acc[4][4];
#pragma unroll
  for (int i = 0; i < 4; ++i)
#pragma unroll
    for (int j = 0; j < 4; ++j) acc[i][j] = (f4){0.f, 0.f, 0.f, 0.f};

  for (int kt = 0; kt < 8; ++kt) {
#pragma unroll
    for (int j = 0; j < 4; ++j) {
      int ci = wv * 4 + j;
      int gci = ci * 64 + lane;
      int r = gci >> 3, cc = gci & 7;
      gl_lds16(Ag + ((size_t)(row0 + r) << 9) + kt * 64 + cc * 8, Al + ci * 512);
      gl_lds16(Bg + ((size_t)(col0 + r) << 9) + kt * 64 + cc * 8, Bl + ci * 512);
    }
    __syncthreads();
#pragma unroll
    for (int kk = 0; kk < 2; ++kk) {
      bf8 af[4], bb[4];
#pragma unroll
      for (int mf = 0; mf < 4; ++mf) {
        int r = wm * 64 + mf * 16 + cl;
        int cc = (kk * 4 + g) ^ (r & 7);
        af[mf] = *(const bf8*)(Al + r * 64 + cc * 8);
      }
#pragma unroll
      for (int nf = 0; nf < 4; ++nf) {
        int r = wn * 64 + nf * 16 + cl;
        int cc = (kk * 4 + g) ^ (r & 7);
        bb[nf] = *(const bf8*)(Bl + r * 64 + cc * 8);
      }
#pragma unroll
      for (int mf = 0; mf < 4; ++mf)
#pragma unroll
        for (int nf = 0; nf < 4; ++nf)
          acc[mf][nf] = __builtin_amdgcn_mfma_f32_16x16x32_bf16(af[mf], bb[nf], acc[mf][nf], 0, 0, 0);
    }
    __syncthreads();
  }

  if (EPI == 1) {
#pragma unroll
    for (int nf = 0; nf < 4; ++nf) {
      int col = col0 + wn * 64 + nf * 16 + cl;
      float bv = bias[col];
#pragma unroll
      for (int mf = 0; mf < 4; ++mf) {
#pragma unroll
        for (int j = 0; j < 4; ++j) {
          int row = row0 + wm * 64 + mf * 16 + 4 * g + j;  // C/D: col=lane&15, row=4*(lane>>4)+reg
          Of[((size_t)row << 9) + col] = acc[mf][nf][j] + bv;
        }
      }
    }
  } else {
    const int which = col0 >> 9;   // block-uniform
#pragma unroll
    for (int nf = 0; nf < 4; ++nf) {
      int col = col0 + wn * 64 + nf * 16 + cl;
      float bv = bias[col];
      int d = col & 63, h = (col >> 6) & 7;
#pragma unroll
      for (int mf = 0; mf < 4; ++mf) {
        int row = row0 + wm * 64 + mf * 16 + 4 * g;   // j = 0 row
        int b = row >> 11, s = row & 2047;
        size_t fb = ((size_t)b * 8 + h) * 131072;     // per-(b,h) fragment array
        if (which == 0) {
          // Q frag: [q16][kk][lane][8]; val = Q[s=q16*16+cl][d=kk*32+g*8+j]
#pragma unroll
          for (int j = 0; j < 4; ++j) {
            int ss = s + j;
            size_t off = fb + (size_t)((ss >> 4) * 1024 + (d >> 5) * 512 +
                                       (((d >> 3) & 3) * 16 + (ss & 15)) * 8 + (d & 7));
            Oq[off] = f2bf((acc[mf][nf][j] + bv) * 0.125f);   // fold softmax scale
          }
        } else if (which == 1) {
          // K frag: [kt][kk][ct][lane][8]; val = K[s=kt*64+ct*16+cl][d=kk*32+g*8+j]
#pragma unroll
          for (int j = 0; j < 4; ++j) {
            int ss = s + j;
            size_t off = fb + (size_t)((ss >> 6) * 4096 + (d >> 5) * 2048 + ((ss >> 4) & 3) * 512 +
                                       (((d >> 3) & 3) * 16 + (ss & 15)) * 8 + (d & 7));
            Ok[off] = f2bf(acc[mf][nf][j] + bv);
          }
        } else {
          // V frag: [kt][kk][ct][lane][8]; val = V[s=kt*64+kk*32+g*8+j][d=ct*16+cl]
          us4 o;
#pragma unroll
          for (int j = 0; j < 4; ++j) o[j] = f2bf(acc[mf][nf][j] + bv);
          size_t off = fb + (size_t)((s >> 6) * 4096 + ((s >> 5) & 1) * 2048 + (d >> 4) * 512 +
                                     ((((s >> 3) & 3) * 16) + (d & 15)) * 8 + (s & 7));
          *(us4*)(Ov + off) = o;
        }
      }
    }
  }
}

// ------------------------------- flash attention --------------------------------
// block = (b, h, pair i); TWO SEQUENTIAL passes: slab A (q16=4i+wv, k 0..i) then
// slab B (q16=4(31-i)+wv, k 0..31-i). Per tile: ALL loads (K, V, rel) issued at
// top — FIFO vmcnt lets QK^T wait on K only; V/rel land under QK^T+softmax.
template <bool RELT>
__global__ __launch_bounds__(256, 4)
void k_attn(const unsigned short* __restrict__ Qf, const unsigned short* __restrict__ Kf,
            const unsigned short* __restrict__ Vf, const float* __restrict__ rel,
            const unsigned short* __restrict__ relt, unsigned short* __restrict__ AO) {
  __shared__ __align__(16) unsigned short Pl[4][16 * 68];
  const int tid = threadIdx.x, wv = tid >> 6, lane = tid & 63, g = lane >> 4, cl = lane & 15;
  // XCD swizzle: the 8 batches sharing relt panel (h,i) have equal bid%8 -> same XCD L2.
  int bid = blockIdx.x;                        // 1024 uniform blocks
  int glo = bid & 7, b = (bid >> 3) & 7, chi = bid >> 6;
  int c = chi * 8 + glo;                       // 0..127
  int h = c >> 4, i = c & 15;                  // pair index i = 0..15
  size_t fb = (((size_t)b << 3) + h) * 131072;
  const unsigned short* Qp = Qf + fb;
  const unsigned short* Kp = Kf + fb;
  const unsigned short* Vp = Vf + fb;
  const float* relp = rel + ((size_t)h << 22);
  unsigned short* pw = Pl[wv];

  for (int pass = 0; pass < 2; ++pass) {
    const int slab = pass ? (31 - i) : i;      // 0..31
    const int q16 = 4 * slab + wv;
    const int rX = q16 << 4;
    const int ktop = slab;                     // diagonal k-tile index

    bf8 qf[2];
#pragma unroll
    for (int kk = 0; kk < 2; ++kk)
      qf[kk] = *(const bf8*)(Qp + q16 * 1024 + kk * 512 + lane * 8);

    f4 oa[4];
    float mr[4], lr[4];
#pragma unroll
    for (int j = 0; j < 4; ++j) { mr[j] = -1e30f; lr[j] = 0.f; }
#pragma unroll
    for (int ct = 0; ct < 4; ++ct) oa[ct] = (f4){0.f, 0.f, 0.f, 0.f};

    for (int kt = 0; kt <= ktop; ++kt) {
      const int kb = kt << 6;
      const unsigned short* Kt = Kp + kt * 4096;
      const unsigned short* Vt = Vp + kt * 4096;
      // ---- ALL loads up front: K (QK^T dep), then V, then rel (FIFO vmcnt) ----
      bf8 kf[2][4], vf[2][4];
#pragma unroll
      for (int kk = 0; kk < 2; ++kk)
#pragma unroll
        for (int ct = 0; ct < 4; ++ct)
          kf[kk][ct] = *(const bf8*)(Kt + kk * 2048 + ct * 512 + lane * 8);
#pragma unroll
      for (int kk = 0; kk < 2; ++kk)
#pragma unroll
        for (int ct = 0; ct < 4; ++ct)
          vf[kk][ct] = *(const bf8*)(Vt + kk * 2048 + ct * 512 + lane * 8);
      us4 rt4[4];
      float rl[4][4];
      if constexpr (RELT) {
        const unsigned short* tb = relt + (((((size_t)h << 7) | q16) << 5) | kt) * 1024;
#pragma unroll
        for (int ct = 0; ct < 4; ++ct)
          rt4[ct] = *(const us4*)(tb + ((ct << 6) | lane) * 4);
      } else {
        const float* rb = relp + ((size_t)(rX + 4 * g) << 11) + kb + cl;
#pragma unroll
        for (int ct = 0; ct < 4; ++ct)
#pragma unroll
          for (int j = 0; j < 4; ++j) rl[ct][j] = rb[((size_t)j << 11) + ct * 16];
      }
      // ---- QK^T (waits on kf only) ----
      f4 sa[4];
#pragma unroll
      for (int ct = 0; ct < 4; ++ct) sa[ct] = (f4){0.f, 0.f, 0.f, 0.f};
#pragma unroll
      for (int kk = 0; kk < 2; ++kk)
#pragma unroll
        for (int ct = 0; ct < 4; ++ct)
          sa[ct] = __builtin_amdgcn_mfma_f32_16x16x32_bf16(qf[kk], kf[kk][ct], sa[ct], 0, 0, 0);
      // ---- rel_pos add ----
      if constexpr (RELT) {
#pragma unroll
        for (int ct = 0; ct < 4; ++ct)
#pragma unroll
          for (int j = 0; j < 4; ++j)
            sa[ct][j] += __builtin_bit_cast(float, (unsigned)rt4[ct][j] << 16);
      } else {
#pragma unroll
        for (int ct = 0; ct < 4; ++ct)
#pragma unroll
          for (int j = 0; j < 4; ++j) sa[ct][j] += rl[ct][j];
      }
      // ---- causal mask (diagonal tile only) ----
      if (kt == ktop) {
#pragma unroll
        for (int ct = 0; ct < 4; ++ct) {
          int kcol = kb + ct * 16 + cl;
#pragma unroll
          for (int j = 0; j < 4; ++j)
            if (kcol > rX + 4 * g + j) sa[ct][j] = -1e30f;
        }
      }
      // ---- online softmax (rows in 16-lane groups) ----
      float al[4];
#pragma unroll
      for (int j = 0; j < 4; ++j) {
        float m0 = fmaxf(fmaxf(sa[0][j], sa[1][j]), fmaxf(sa[2][j], sa[3][j]));
        m0 = fmaxf(m0, __shfl_xor(m0, 1, 16));
        m0 = fmaxf(m0, __shfl_xor(m0, 2, 16));
        m0 = fmaxf(m0, __shfl_xor(m0, 4, 16));
        m0 = fmaxf(m0, __shfl_xor(m0, 8, 16));
        float mn = fmaxf(mr[j], m0);
        al[j] = __expf(mr[j] - mn);
        mr[j] = mn;
      }
#pragma unroll
      for (int ct = 0; ct < 4; ++ct)
#pragma unroll
        for (int j = 0; j < 4; ++j) sa[ct][j] = __expf(sa[ct][j] - mr[j]);
#pragma unroll
      for (int j = 0; j < 4; ++j) {
        float rs = sa[0][j] + sa[1][j] + sa[2][j] + sa[3][j];
        rs += __shfl_xor(rs, 1, 16);
        rs += __shfl_xor(rs, 2, 16);
        rs += __shfl_xor(rs, 4, 16);
        rs += __shfl_xor(rs, 8, 16);
        lr[j] = lr[j] * al[j] + rs;
      }
#pragma unroll
      for (int ct = 0; ct < 4; ++ct) {
        oa[ct][0] *= al[0]; oa[ct][1] *= al[1]; oa[ct][2] *= al[2]; oa[ct][3] *= al[3];
      }
      // ---- P -> LDS transpose (wave-private; compiler cvt_pk pairs) ----
#pragma unroll
      for (int ct = 0; ct < 4; ++ct)
#pragma unroll
        for (int j = 0; j < 4; ++j)
          pw[(4 * g + j) * 68 + ct * 16 + cl] = cbf(sa[ct][j]);
      // ---- PV (vf already resident) ----
#pragma unroll
      for (int kk = 0; kk < 2; ++kk) {
        us4 p0 = *(const us4*)(pw + cl * 68 + kk * 32 + g * 8);
        us4 p1 = *(const us4*)(pw + cl * 68 + kk * 32 + g * 8 + 4);
        bf8 pf = comb(p0, p1);
#pragma unroll
        for (int ct = 0; ct < 4; ++ct)
          oa[ct] = __builtin_amdgcn_mfma_f32_16x16x32_bf16(pf, vf[kk][ct], oa[ct], 0, 0, 0);
      }
    }
    // ---- epilogue for this slab: O /= l, chunk-swizzled bf16 write ----
#pragma unroll
    for (int j = 0; j < 4; ++j) {
      float inv = 1.0f / lr[j];
      int s = rX + 4 * g + j;
#pragma unroll
      for (int ct = 0; ct < 4; ++ct) {
        int d = ct * 16 + cl;
        int d2 = (d & 7) | (((d >> 3) ^ (s & 7)) << 3);
        AO[(((size_t)b << 11) + s) * 512 + h * 64 + d2] = cbf(oa[ct][j] * inv);
      }
    }
  }
}

// ------------------------------------ launch ------------------------------------
extern "C" void kernel_launch(void* const* d_in, const int* in_sizes, int n_in,
                              void* d_out, int out_size, void* d_ws, size_t ws_size,
                              hipStream_t stream) {
  const float* x    = (const float*)d_in[0];
  const float* Wqkv = (const float*)d_in[1];
  const float* bqkv = (const float*)d_in[2];
  const float* Wout = (const float*)d_in[3];
  const float* bout = (const float*)d_in[4];
  const float* rel  = (const float*)d_in[5];
  float* out = (float*)d_out;

  unsigned short* Qw  = (unsigned short*)d_ws;
  unsigned short* Kw  = Qw  + 8388608;
  unsigned short* Vw  = Kw  + 8388608;
  unsigned short* XA  = Vw  + 8388608;    // Xb (pre-attn) then AO (post-attn)
  unsigned short* WtQ = XA  + 8388608;
  unsigned short* WtO = WtQ + 786432;
  unsigned short* relt= WtO + 262144;
  const bool useT = ws_size >= (34603008ULL + 33554432ULL) * 2ULL;  // base + rel table

  k_convert_x<<<dim3(4096), dim3(256), 0, stream>>>(x, XA);
  k_transpose_w<<<dim3(16, 48), dim3(256), 0, stream>>>(Wqkv, WtQ, 1536);
  k_transpose_w<<<dim3(16, 16), dim3(256), 0, stream>>>(Wout, WtO, 512);
  if (useT) k_relconv<<<dim3(32768), dim3(256), 0, stream>>>(rel, relt);
  k_gemm<0><<<dim3(128, 12), dim3(256), 0, stream>>>(XA, WtQ, bqkv, nullptr, Qw, Kw, Vw);
  if (useT) k_attn<true ><<<dim3(1024), dim3(256), 0, stream>>>(Qw, Kw, Vw, rel, relt, XA);
  else      k_attn<false><<<dim3(1024), dim3(256), 0, stream>>>(Qw, Kw, Vw, rel, relt, XA);
  k_gemm<1><<<dim3(128, 4), dim3(256), 0, stream>>>(XA, WtO, bout, out, nullptr, nullptr, nullptr);
}